// Round 2
// baseline (620.193 us; speedup 1.0000x reference)
//
#include <hip/hip_runtime.h>
#include <hip/hip_bf16.h>

#define B_  8
#define T_  4096
#define D_  1024
#define H_  16
#define DH_ 64
#define NC_ 4          // T-chunks in k_pv

typedef __bf16 bf8 __attribute__((ext_vector_type(8)));
typedef float f32x4 __attribute__((ext_vector_type(4)));

__device__ __forceinline__ unsigned short f2bf_rn(float f) {
    unsigned u = __float_as_uint(f);
    unsigned r = (u + 0x7FFF + ((u >> 16) & 1)) >> 16;
    return (unsigned short)r;
}

__device__ __forceinline__ void async_load16(const void* gp, void* lp) {
    __builtin_amdgcn_global_load_lds(
        (const __attribute__((address_space(1))) unsigned*)(gp),
        (__attribute__((address_space(3))) unsigned*)(lp), 16, 0, 0);
}

// ---------------- small helpers ----------------

__global__ void k_sel(const int* __restrict__ idx, int* __restrict__ sel, int U) {
    for (int t = threadIdx.x; t < T_; t += 256) sel[t] = 0;
    __syncthreads();
    if (threadIdx.x < U) sel[idx[threadIdx.x]] = threadIdx.x + 1;
}

__global__ void k_gather(const float* __restrict__ x, const int* __restrict__ idx,
                         float* __restrict__ xs, int U) {
    int bi = blockIdx.x;
    int b = bi / U, i = bi - b * U;
    int t = idx[i];
    const float4* src = (const float4*)(x + ((size_t)(b * T_ + t)) * D_);
    float4* dst = (float4*)(xs + (size_t)bi * D_);
    dst[threadIdx.x] = src[threadIdx.x];
}

__global__ void k_cvt_flat(const float* __restrict__ src, short* __restrict__ dst) {
    size_t i = ((size_t)blockIdx.x * 256 + threadIdx.x) * 8;
    float4 a = *(const float4*)(src + i);
    float4 b = *(const float4*)(src + i + 4);
    short4 s0, s1;
    s0.x = (short)f2bf_rn(a.x); s0.y = (short)f2bf_rn(a.y);
    s0.z = (short)f2bf_rn(a.z); s0.w = (short)f2bf_rn(a.w);
    s1.x = (short)f2bf_rn(b.x); s1.y = (short)f2bf_rn(b.y);
    s1.z = (short)f2bf_rn(b.z); s1.w = (short)f2bf_rn(b.w);
    *(short4*)(dst + i) = s0;
    *(short4*)(dst + i + 4) = s1;
}

__global__ void k_zpad(short* __restrict__ Qtb, int HU, int MP) {
    int bi = blockIdx.x;
    int npad = MP - HU;
    int b = bi / npad, r = bi - b * npad;
    short4 z = {0, 0, 0, 0};
    *(short4*)(Qtb + ((size_t)b * MP + HU + r) * D_ + threadIdx.x * 4) = z;
}

// ---------------- fp32 tiled projection ----------------
__global__ __launch_bounds__(256) void k_proj(const float* __restrict__ A,
                                              const float* __restrict__ W,
                                              const float* __restrict__ bias,
                                              float* __restrict__ C, int M) {
    __shared__ float As[32][64 + 4];
    __shared__ float Bs[32][64 + 4];
    int m0 = blockIdx.x * 64, n0 = blockIdx.y * 64;
    int tid = threadIdx.x;
    int lr = tid >> 3;
    int lc = (tid & 7) * 4;
    int ty = tid >> 4, tx = tid & 15;
    float acc[4][4] = {{0.f}};
    for (int k0 = 0; k0 < D_; k0 += 32) {
#pragma unroll
        for (int half = 0; half < 2; ++half) {
            int r = lr + half * 32;
            int gm = m0 + r;
            float4 v = make_float4(0.f, 0.f, 0.f, 0.f);
            if (gm < M) v = *(const float4*)(A + (size_t)gm * D_ + k0 + lc);
            As[lc + 0][r] = v.x; As[lc + 1][r] = v.y; As[lc + 2][r] = v.z; As[lc + 3][r] = v.w;
            int gn = n0 + r;
            float4 w = *(const float4*)(W + (size_t)gn * D_ + k0 + lc);
            Bs[lc + 0][r] = w.x; Bs[lc + 1][r] = w.y; Bs[lc + 2][r] = w.z; Bs[lc + 3][r] = w.w;
        }
        __syncthreads();
#pragma unroll
        for (int kk = 0; kk < 32; ++kk) {
            float4 a = *(const float4*)&As[kk][ty * 4];
            float4 bb = *(const float4*)&Bs[kk][tx * 4];
            acc[0][0] += a.x * bb.x; acc[0][1] += a.x * bb.y; acc[0][2] += a.x * bb.z; acc[0][3] += a.x * bb.w;
            acc[1][0] += a.y * bb.x; acc[1][1] += a.y * bb.y; acc[1][2] += a.y * bb.z; acc[1][3] += a.y * bb.w;
            acc[2][0] += a.z * bb.x; acc[2][1] += a.z * bb.y; acc[2][2] += a.z * bb.z; acc[2][3] += a.z * bb.w;
            acc[3][0] += a.w * bb.x; acc[3][1] += a.w * bb.y; acc[3][2] += a.w * bb.z; acc[3][3] += a.w * bb.w;
        }
        __syncthreads();
    }
#pragma unroll
    for (int i = 0; i < 4; ++i) {
        int gm = m0 + ty * 4 + i;
        if (gm < M) {
            int gn = n0 + tx * 4;
            float4 v = make_float4(acc[i][0], acc[i][1], acc[i][2], acc[i][3]);
            if (bias) {
                v.x += bias[gn + 0]; v.y += bias[gn + 1];
                v.z += bias[gn + 2]; v.w += bias[gn + 3];
            }
            *(float4*)(C + (size_t)gm * D_ + gn) = v;
        }
    }
}

// ---------------- per-head Qt GEMM (writes bf16, 0.125-scaled) ----------------
__global__ __launch_bounds__(256) void k_qth(const float* __restrict__ Qs,
                                             const float* __restrict__ Wk,
                                             short* __restrict__ Qtb, int U, int MP) {
    __shared__ float As[32][64 + 4];
    __shared__ float Bs[32][64 + 4];
    int h = blockIdx.z;
    int m0 = blockIdx.x * 64, n0 = blockIdx.y * 64;
    int BU = B_ * U;
    int tid = threadIdx.x;
    int lr = tid >> 3, lc = (tid & 7) * 4;
    int ty = tid >> 4, tx = tid & 15;
    float acc[4][4] = {{0.f}};
    for (int k0 = 0; k0 < DH_; k0 += 32) {
#pragma unroll
        for (int half = 0; half < 2; ++half) {
            int r = lr + half * 32;
            int gm = m0 + r;
            float4 v = make_float4(0.f, 0.f, 0.f, 0.f);
            if (gm < BU) v = *(const float4*)(Qs + (size_t)gm * D_ + h * DH_ + k0 + lc);
            As[lc + 0][r] = v.x; As[lc + 1][r] = v.y; As[lc + 2][r] = v.z; As[lc + 3][r] = v.w;
            int kr = (tid >> 4) + half * 16;
            int nc = (tid & 15) * 4;
            float4 w = *(const float4*)(Wk + ((size_t)(h * DH_ + k0 + kr)) * D_ + n0 + nc);
            *(float4*)&Bs[kr][nc] = w;
        }
        __syncthreads();
#pragma unroll
        for (int kk = 0; kk < 32; ++kk) {
            float4 a = *(const float4*)&As[kk][ty * 4];
            float4 bb = *(const float4*)&Bs[kk][tx * 4];
            acc[0][0] += a.x * bb.x; acc[0][1] += a.x * bb.y; acc[0][2] += a.x * bb.z; acc[0][3] += a.x * bb.w;
            acc[1][0] += a.y * bb.x; acc[1][1] += a.y * bb.y; acc[1][2] += a.y * bb.z; acc[1][3] += a.y * bb.w;
            acc[2][0] += a.z * bb.x; acc[2][1] += a.z * bb.y; acc[2][2] += a.z * bb.z; acc[2][3] += a.z * bb.w;
            acc[3][0] += a.w * bb.x; acc[3][1] += a.w * bb.y; acc[3][2] += a.w * bb.z; acc[3][3] += a.w * bb.w;
        }
        __syncthreads();
    }
#pragma unroll
    for (int i = 0; i < 4; ++i) {
        int gm = m0 + ty * 4 + i;
        if (gm < BU) {
            int b = gm / U, ii = gm - b * U;
            short4 s;
            s.x = (short)f2bf_rn(0.125f * acc[i][0]);
            s.y = (short)f2bf_rn(0.125f * acc[i][1]);
            s.z = (short)f2bf_rn(0.125f * acc[i][2]);
            s.w = (short)f2bf_rn(0.125f * acc[i][3]);
            *(short4*)(Qtb + ((size_t)b * MP + h * U + ii) * D_ + n0 + tx * 4) = s;
        }
    }
}

// ================= 256x256 bf16 MFMA core — 8-phase schedule (T3+T4+T5) =================
// 512 threads = 8 waves (2M x 4N), per-wave C = 128x64 (acc[8][4]).
// LDS per matrix: 2 dbuf x 2 khalf x [4 slots-of-16B][256 rows] (slot-major, 32 KiB each;
// total A+B = 128 KiB). Slot-major => global_load_lds dest is lane-linear AND frag
// ds_read_b128 is bank-balanced (8 lanes per 4-bank group) with no XOR swizzle.
// Per K-tile (BK=64): 4 phases, each {ds_read subtile | stage 1 half-tile (2 gload_lds)
// | barrier | lgkmcnt(0) | setprio(1) 16 MFMA setprio(0) | [counted vmcnt] | barrier}.
// vmcnt(4) twice per K-tile (never 0 in steady state): allows the 2 newest half-tiles
// (4 loads) to stay in flight across barriers.
#define GEMM_NT 16   // K = 1024 / BK = 64

__device__ __forceinline__ void gemm256_8ph(const short* __restrict__ Ag,
                                            const short* __restrict__ Bg,
                                            short* __restrict__ lA0,
                                            short* __restrict__ lB0,
                                            f32x4 (&acc)[8][4]) {
    const int tid = threadIdx.x;
    const int lane = tid & 63, w = tid >> 6;
    const int wr = w >> 2, wc = w & 3;
    const int ln = lane & 15, q = lane >> 4;
#pragma unroll
    for (int mi = 0; mi < 8; ++mi)
#pragma unroll
        for (int ni = 0; ni < 4; ++ni)
            acc[mi][ni] = (f32x4){0.f, 0.f, 0.f, 0.f};

    // staging: half-tile = one matrix x one K-half = 256 rows x 32 cols = 1024 x 16B slots
    // thread covers li = tid and 512+tid; (row = li&255, slot = li>>8);
    // LDS dest = region + li*16B (lane-linear); src = G + row*D + kcol + slot*8
    const int li0 = tid, li1 = 512 + tid;
    const size_t ga0 = (size_t)(li0 & 255) * D_ + ((li0 >> 8) << 3);
    const size_t ga1 = (size_t)(li1 & 255) * D_ + ((li1 >> 8) << 3);
    const int ld0 = li0 * 8, ld1 = li1 * 8;   // shorts

#define STAGE(G, l, kcol)                                   \
    do {                                                    \
        async_load16((G) + ga0 + (kcol), (l) + ld0);        \
        async_load16((G) + ga1 + (kcol), (l) + ld1);        \
    } while (0)

    // prologue: K-tile 0 fully (both K-halves of A and B into buf 0)
    STAGE(Ag, lA0, 0);
    STAGE(Bg, lB0, 0);
    STAGE(Ag, lA0 + 8192, 32);
    STAGE(Bg, lB0 + 8192, 32);
    asm volatile("s_waitcnt vmcnt(0)" ::: "memory");
    __builtin_amdgcn_s_barrier();

    // frag read offsets (shorts): region + q*2048 + row*8; rows step 16 -> +128
    const int aoff = q * 2048 + (wr * 128 + ln) * 8;
    const int boff = q * 2048 + (wc * 64 + ln) * 8;

#pragma unroll 1
    for (int t = 0; t < GEMM_NT; ++t) {
        const int p = t & 1, pn = p ^ 1;
        const short* pA = lA0 + p * 16384;
        const short* pB = lB0 + p * 16384;
        short* nA = lA0 + pn * 16384;
        short* nB = lB0 + pn * 16384;
        const int kn = (t + 1) * 64;
        const bool more = (t + 1 < GEMM_NT);
        bf8 af[4], bf[4];

        // ---- phase 0: kh0, acc rows 0-3 ----
#pragma unroll
        for (int ni = 0; ni < 4; ++ni) bf[ni] = *(const bf8*)(pB + boff + ni * 128);
#pragma unroll
        for (int mi = 0; mi < 4; ++mi) af[mi] = *(const bf8*)(pA + aoff + mi * 128);
        if (more) STAGE(Ag, nA, kn);
        __builtin_amdgcn_s_barrier();
        asm volatile("s_waitcnt lgkmcnt(0)" ::: "memory");
        __builtin_amdgcn_s_setprio(1);
#pragma unroll
        for (int mi = 0; mi < 4; ++mi)
#pragma unroll
            for (int ni = 0; ni < 4; ++ni)
                acc[mi][ni] = __builtin_amdgcn_mfma_f32_16x16x32_bf16(af[mi], bf[ni], acc[mi][ni], 0, 0, 0);
        __builtin_amdgcn_s_setprio(0);
        __builtin_amdgcn_s_barrier();

        // ---- phase 1: kh0, acc rows 4-7 (B frags reused in regs) ----
#pragma unroll
        for (int mi = 0; mi < 4; ++mi) af[mi] = *(const bf8*)(pA + aoff + 512 + mi * 128);
        if (more) STAGE(Bg, nB, kn);
        __builtin_amdgcn_s_barrier();
        asm volatile("s_waitcnt lgkmcnt(0)" ::: "memory");
        __builtin_amdgcn_s_setprio(1);
#pragma unroll
        for (int mi = 0; mi < 4; ++mi)
#pragma unroll
            for (int ni = 0; ni < 4; ++ni)
                acc[4 + mi][ni] = __builtin_amdgcn_mfma_f32_16x16x32_bf16(af[mi], bf[ni], acc[4 + mi][ni], 0, 0, 0);
        __builtin_amdgcn_s_setprio(0);
        // certify kh1(t) for phase-2 ds_reads (2 newest half-tiles = this tile's
        // phase-0/1 stage issues may remain in flight). Last tile: nothing newer -> 0.
        if (more) asm volatile("s_waitcnt vmcnt(4)" ::: "memory");
        else      asm volatile("s_waitcnt vmcnt(0)" ::: "memory");
        __builtin_amdgcn_s_barrier();

        // ---- phase 2: kh1, acc rows 0-3 ----
#pragma unroll
        for (int ni = 0; ni < 4; ++ni) bf[ni] = *(const bf8*)(pB + 8192 + boff + ni * 128);
#pragma unroll
        for (int mi = 0; mi < 4; ++mi) af[mi] = *(const bf8*)(pA + 8192 + aoff + mi * 128);
        if (more) STAGE(Ag, nA + 8192, kn + 32);
        __builtin_amdgcn_s_barrier();
        asm volatile("s_waitcnt lgkmcnt(0)" ::: "memory");
        __builtin_amdgcn_s_setprio(1);
#pragma unroll
        for (int mi = 0; mi < 4; ++mi)
#pragma unroll
            for (int ni = 0; ni < 4; ++ni)
                acc[mi][ni] = __builtin_amdgcn_mfma_f32_16x16x32_bf16(af[mi], bf[ni], acc[mi][ni], 0, 0, 0);
        __builtin_amdgcn_s_setprio(0);
        __builtin_amdgcn_s_barrier();

        // ---- phase 3: kh1, acc rows 4-7 ----
#pragma unroll
        for (int mi = 0; mi < 4; ++mi) af[mi] = *(const bf8*)(pA + 8192 + aoff + 512 + mi * 128);
        if (more) STAGE(Bg, nB + 8192, kn + 32);
        __builtin_amdgcn_s_barrier();
        asm volatile("s_waitcnt lgkmcnt(0)" ::: "memory");
        __builtin_amdgcn_s_setprio(1);
#pragma unroll
        for (int mi = 0; mi < 4; ++mi)
#pragma unroll
            for (int ni = 0; ni < 4; ++ni)
                acc[4 + mi][ni] = __builtin_amdgcn_mfma_f32_16x16x32_bf16(af[mi], bf[ni], acc[4 + mi][ni], 0, 0, 0);
        __builtin_amdgcn_s_setprio(0);
        // certify kh0(t+1) for next phase-0 ds_reads; allow kh1(t+1) stages in flight
        asm volatile("s_waitcnt vmcnt(4)" ::: "memory");
        __builtin_amdgcn_s_barrier();
    }
#undef STAGE
}

// ---------------- scores GEMM + fused exp (256x256 8-phase core) ----------------
__global__ __launch_bounds__(512, 2) void k_scores2(const short* __restrict__ Qtb,
                                                    const short* __restrict__ xb,
                                                    short* __restrict__ attnb, int MP) {
    __shared__ short lA[2][16384];
    __shared__ short lB[2][16384];
    int bid = blockIdx.x;
    int lg = (bid & 7) * (gridDim.x >> 3) + (bid >> 3);   // bijective XCD swizzle
    int MT = MP >> 8;                  // 256-row m-tiles (MP=768 -> 3)
    int per_b = MT << 4;               // 16 n-tiles
    int b = lg / per_b;
    int r = lg - b * per_b;
    int mt = r >> 4, nt = r & 15;
    const short* Ag = Qtb + ((size_t)b * MP + mt * 256) * D_;
    const short* Bg = xb + ((size_t)b * T_ + nt * 256) * D_;
    f32x4 acc[8][4];
    gemm256_8ph(Ag, Bg, &lA[0][0], &lB[0][0], acc);

    short* Cb = attnb + (size_t)b * MP * T_;
    int tid = threadIdx.x;
    int lane = tid & 63, w = tid >> 6;
    int wr = w >> 2, wc = w & 3;
    int ln = lane & 15, q = lane >> 4;
    int row0 = mt * 256 + wr * 128;
    int col0 = nt * 256 + wc * 64;
#pragma unroll
    for (int mi = 0; mi < 8; ++mi)
#pragma unroll
        for (int ni = 0; ni < 4; ++ni) {
            int col = col0 + ni * 16 + ln;
#pragma unroll
            for (int rr = 0; rr < 4; ++rr) {
                int grow = row0 + mi * 16 + q * 4 + rr;
                Cb[(size_t)grow * T_ + col] = (short)f2bf_rn(__expf(acc[mi][ni][rr]));
            }
        }
}

// ---------------- V GEMM (8-phase core) + transpose epilogue to Vt[(b*H+h)*64+dh][t] ----------------
__global__ __launch_bounds__(512, 2) void k_v2(const short* __restrict__ xb,
                                               const short* __restrict__ Wvb,
                                               short* __restrict__ Vt) {
    __shared__ short lA[2][16384];
    __shared__ short lB[2][16384];
    int bid = blockIdx.x;
    int lg = (bid & 7) * (gridDim.x >> 3) + (bid >> 3);   // 512 blocks, 64/XCD
    int mt = lg >> 2, nt = lg & 3;     // mt: 128 t-tiles, nt: 4 head-group tiles
    const short* Ag = xb + (size_t)mt * 256 * D_;
    const short* Bg = Wvb + (size_t)nt * 256 * D_;
    f32x4 acc[8][4];
    gemm256_8ph(Ag, Bg, &lA[0][0], &lB[0][0], acc);

    // epilogue: per-wave transpose (t, dh) -> (dh, t) via LDS, 4 passes of 16 dh
    int tid = threadIdx.x;
    int lane = tid & 63, w = tid >> 6;
    int wr = w >> 2, wc = w & 3;
    int ln = lane & 15, q = lane >> 4;
    int h = nt * 4 + wc;               // this wave owns one full head
    int b = mt >> 4;
    int tIn = (mt & 15) * 256 + wr * 128;
    const int PITCH = 136;             // shorts per dh row (128 t + pad)
    short* ep = &lA[0][0] + w * 2304;  // 2176 needed, 2304 alloc'd per wave
    size_t vbase = ((size_t)(b * H_ + h) * DH_) * T_;
    __syncthreads();                   // all waves past core reads before scratch reuse
#pragma unroll
    for (int ni = 0; ni < 4; ++ni) {
#pragma unroll
        for (int mi = 0; mi < 8; ++mi) {
            short4 s;
            s.x = (short)f2bf_rn(acc[mi][ni][0]);
            s.y = (short)f2bf_rn(acc[mi][ni][1]);
            s.z = (short)f2bf_rn(acc[mi][ni][2]);
            s.w = (short)f2bf_rn(acc[mi][ni][3]);
            *(short4*)(ep + ln * PITCH + mi * 16 + q * 4) = s;
        }
        __syncthreads();
#pragma unroll
        for (int it = 0; it < 2; ++it) {
            int dhl = it * 8 + (lane >> 3);
            int seg = lane & 7;
            bf8 v0 = *(const bf8*)(ep + dhl * PITCH + seg * 8);
            bf8 v1 = *(const bf8*)(ep + dhl * PITCH + (seg + 8) * 8);
            int dh = ni * 16 + dhl;
            *(bf8*)(Vt + vbase + (size_t)dh * T_ + tIn + seg * 8) = v0;
            *(bf8*)(Vt + vbase + (size_t)dh * T_ + tIn + 64 + seg * 8) = v1;
        }
        __syncthreads();
    }
}

// ---------------- PV flash: O_partial, rs_partial per (b,h,chunk) ----------------
__global__ __launch_bounds__(256) void k_pv(const short* __restrict__ attnb,
                                            const short* __restrict__ Vt,
                                            float* __restrict__ Op,
                                            float* __restrict__ rsp,
                                            int U, int MP) {
    __shared__ short vt[64 * 136];
    int gid = blockIdx.x;
    int c = gid & (NC_ - 1);
    int bh = gid >> 2;
    int h = bh & (H_ - 1);
    int b = bh >> 4;
    int tid = threadIdx.x;
    int lane = tid & 63, w = tid >> 6;
    int quad = lane >> 4;
    const short* Arow = attnb + ((size_t)b * MP + h * U) * T_;
    const short* Vrow = Vt + (size_t)bh * DH_ * T_;

    f32x4 O[3];
#pragma unroll
    for (int mi = 0; mi < 3; ++mi) O[mi] = (f32x4){0.f, 0.f, 0.f, 0.f};
    float rs[3] = {0.f, 0.f, 0.f};

    for (int tt = 0; tt < (T_ / NC_) / 128; ++tt) {
        int t0 = c * (T_ / NC_) + tt * 128;
#pragma unroll
        for (int it = 0; it < 4; ++it) {
            int idx = it * 256 + tid;
            int dh = idx >> 4, seg = idx & 15;
            bf8 v = *(const bf8*)(Vrow + (size_t)dh * T_ + t0 + seg * 8);
            *(bf8*)(vt + dh * 136 + seg * 8) = v;
        }
        __syncthreads();
        bf8 af[3][4];
#pragma unroll
        for (int mi = 0; mi < 3; ++mi)
#pragma unroll
            for (int kf = 0; kf < 4; ++kf)
                af[mi][kf] = *(const bf8*)(Arow + (size_t)(mi * 16 + (lane & 15)) * T_ + t0 + kf * 32 + quad * 8);
        if (w == 0) {
#pragma unroll
            for (int mi = 0; mi < 3; ++mi)
#pragma unroll
                for (int kf = 0; kf < 4; ++kf)
#pragma unroll
                    for (int j = 0; j < 8; ++j) rs[mi] += (float)af[mi][kf][j];
        }
#pragma unroll
        for (int kf = 0; kf < 4; ++kf) {
            bf8 bfr = *(const bf8*)(vt + (w * 16 + (lane & 15)) * 136 + kf * 32 + quad * 8);
#pragma unroll
            for (int mi = 0; mi < 3; ++mi)
                O[mi] = __builtin_amdgcn_mfma_f32_16x16x32_bf16(af[mi][kf], bfr, O[mi], 0, 0, 0);
        }
        __syncthreads();
    }
#pragma unroll
    for (int mi = 0; mi < 3; ++mi)
#pragma unroll
        for (int r = 0; r < 4; ++r)
            Op[((size_t)gid * 48 + mi * 16 + quad * 4 + r) * DH_ + w * 16 + (lane & 15)] = O[mi][r];
    if (w == 0) {
#pragma unroll
        for (int mi = 0; mi < 3; ++mi) {
            rs[mi] += __shfl_xor(rs[mi], 16);
            rs[mi] += __shfl_xor(rs[mi], 32);
            if (quad == 0) rsp[(size_t)gid * 48 + mi * 16 + lane] = rs[mi];
        }
    }
}

// ---------------- reduce chunks, normalize, assemble R ----------------
__global__ __launch_bounds__(256) void k_rows2(const float* __restrict__ Op,
                                               const float* __restrict__ rsp,
                                               float* __restrict__ R, int U) {
    __shared__ float inv[48];
    __shared__ float msum[4][64];
    int bh = blockIdx.x;
    int b = bh >> 4, h = bh & (H_ - 1);
    int tid = threadIdx.x;
    if (tid < 48) {
        float s = 0.f;
        for (int cc = 0; cc < NC_; ++cc) s += rsp[(size_t)(bh * NC_ + cc) * 48 + tid];
        inv[tid] = 1.f / s;
    }
    __syncthreads();
    int dh = tid & 63, ig = tid >> 6;
    float acc = 0.f;
    for (int p = 0; p < 11; ++p) {
        int i = p * 4 + ig;
        if (i < U) {
            float o = 0.f;
            for (int cc = 0; cc < NC_; ++cc)
                o += Op[((size_t)(bh * NC_ + cc) * 48 + i) * DH_ + dh];
            float v = o * inv[i];
            R[((size_t)b * (U + 1) + 1 + i) * D_ + h * DH_ + dh] = v;
            acc += v;
        }
    }
    msum[ig][dh] = acc;
    __syncthreads();
    if (ig == 0)
        R[((size_t)b * (U + 1)) * D_ + h * DH_ + dh] =
            (msum[0][dh] + msum[1][dh] + msum[2][dh] + msum[3][dh]) / (float)U;
}

__global__ __launch_bounds__(256) void k_fill(const float* __restrict__ Yr,
                                              const int* __restrict__ sel,
                                              float* __restrict__ y, int U) {
    int blk = blockIdx.x;
    int b = blk >> 12, t = blk & (T_ - 1);
    int j = sel[t];
    const float4* src = (const float4*)(Yr + ((size_t)b * (U + 1) + j) * D_);
    float4* dst = (float4*)(y + (size_t)blk * D_);
    dst[threadIdx.x] = src[threadIdx.x];
}

extern "C" void kernel_launch(void* const* d_in, const int* in_sizes, int n_in,
                              void* d_out, int out_size, void* d_ws, size_t ws_size,
                              hipStream_t stream) {
    const float* x  = (const float*)d_in[0];
    const float* Wq = (const float*)d_in[1];
    const float* Wk = (const float*)d_in[2];
    const float* Wv = (const float*)d_in[3];
    const float* Wo = (const float*)d_in[4];
    const float* bo = (const float*)d_in[5];
    const int*  idx = (const int*)d_in[6];
    int U = in_sizes[6];                      // 41
    int HU = H_ * U;                          // 656
    int MP = ((HU + 127) / 128) * 128;        // 768

    char* w = (char*)d_ws;
    auto alloc = [&](size_t bytes) { char* p = w; w += (bytes + 255) & ~(size_t)255; return p; };

    float* xs    = (float*)alloc((size_t)B_ * U * D_ * 4);
    float* Qs    = (float*)alloc((size_t)B_ * U * D_ * 4);
    short* Qtb   = (short*)alloc((size_t)B_ * MP * D_ * 2);
    short* xb    = (short*)alloc((size_t)B_ * T_ * D_ * 2);
    short* Wvb   = (short*)alloc((size_t)D_ * D_ * 2);
    short* attnb = (short*)alloc((size_t)B_ * MP * T_ * 2);
    short* Vtb   = (short*)alloc((size_t)B_ * D_ * T_ * 2);
    float* Opb   = (float*)alloc((size_t)B_ * H_ * NC_ * 48 * DH_ * 4);
    float* rspb  = (float*)alloc((size_t)B_ * H_ * NC_ * 48 * 4);
    float* R     = (float*)alloc((size_t)B_ * (U + 1) * D_ * 4);
    float* Yr    = (float*)alloc((size_t)B_ * (U + 1) * D_ * 4);
    int*   sel   = (int*)alloc((size_t)T_ * 4);

    int MT = MP / 256;                        // 3

    k_sel<<<dim3(1), dim3(256), 0, stream>>>(idx, sel, U);
    k_gather<<<dim3(B_ * U), dim3(256), 0, stream>>>(x, idx, xs, U);
    k_proj<<<dim3((B_ * U + 63) / 64, D_ / 64), dim3(256), 0, stream>>>(xs, Wq, nullptr, Qs, B_ * U);
    k_cvt_flat<<<dim3((size_t)B_ * T_ * D_ / 2048), dim3(256), 0, stream>>>(x, xb);
    k_cvt_flat<<<dim3((size_t)D_ * D_ / 2048), dim3(256), 0, stream>>>(Wv, Wvb);
    k_zpad<<<dim3(B_ * (MP - HU)), dim3(256), 0, stream>>>(Qtb, HU, MP);
    k_qth<<<dim3((B_ * U + 63) / 64, D_ / 64, H_), dim3(256), 0, stream>>>(Qs, Wk, Qtb, U, MP);
    k_scores2<<<dim3(B_ * MT * 16), dim3(512), 0, stream>>>(Qtb, xb, attnb, MP);
    k_v2<<<dim3((B_ * T_ / 256) * (D_ / 256)), dim3(512), 0, stream>>>(xb, Wvb, Vtb);
    k_pv<<<dim3(B_ * H_ * NC_), dim3(256), 0, stream>>>(attnb, Vtb, Opb, rspb, U, MP);
    k_rows2<<<dim3(B_ * H_), dim3(256), 0, stream>>>(Opb, rspb, R, U);
    k_proj<<<dim3((B_ * (U + 1) + 63) / 64, D_ / 64), dim3(256), 0, stream>>>(R, Wo, bo, Yr, B_ * (U + 1));
    k_fill<<<dim3(B_ * T_), dim3(256), 0, stream>>>(Yr, sel, (float*)d_out, U);
}

// Round 3
// 579.217 us; speedup vs baseline: 1.0707x; 1.0707x over previous
//
#include <hip/hip_runtime.h>
#include <hip/hip_bf16.h>

#define B_  8
#define T_  4096
#define D_  1024
#define H_  16
#define DH_ 64
#define NC_ 4          // T-chunks in k_pv

typedef __bf16 bf8 __attribute__((ext_vector_type(8)));
typedef float f32x4 __attribute__((ext_vector_type(4)));

__device__ __forceinline__ unsigned short f2bf_rn(float f) {
    unsigned u = __float_as_uint(f);
    unsigned r = (u + 0x7FFF + ((u >> 16) & 1)) >> 16;
    return (unsigned short)r;
}

__device__ __forceinline__ void async_load16(const void* gp, void* lp) {
    __builtin_amdgcn_global_load_lds(
        (const __attribute__((address_space(1))) unsigned*)(gp),
        (__attribute__((address_space(3))) unsigned*)(lp), 16, 0, 0);
}

// ---------------- small helpers ----------------

__global__ void k_sel(const int* __restrict__ idx, int* __restrict__ sel, int U) {
    for (int t = threadIdx.x; t < T_; t += 256) sel[t] = 0;
    __syncthreads();
    if (threadIdx.x < U) sel[idx[threadIdx.x]] = threadIdx.x + 1;
}

__global__ void k_gather(const float* __restrict__ x, const int* __restrict__ idx,
                         float* __restrict__ xs, int U) {
    int bi = blockIdx.x;
    int b = bi / U, i = bi - b * U;
    int t = idx[i];
    const float4* src = (const float4*)(x + ((size_t)(b * T_ + t)) * D_);
    float4* dst = (float4*)(xs + (size_t)bi * D_);
    dst[threadIdx.x] = src[threadIdx.x];
}

__global__ void k_cvt_flat(const float* __restrict__ src, short* __restrict__ dst) {
    size_t i = ((size_t)blockIdx.x * 256 + threadIdx.x) * 8;
    float4 a = *(const float4*)(src + i);
    float4 b = *(const float4*)(src + i + 4);
    short4 s0, s1;
    s0.x = (short)f2bf_rn(a.x); s0.y = (short)f2bf_rn(a.y);
    s0.z = (short)f2bf_rn(a.z); s0.w = (short)f2bf_rn(a.w);
    s1.x = (short)f2bf_rn(b.x); s1.y = (short)f2bf_rn(b.y);
    s1.z = (short)f2bf_rn(b.z); s1.w = (short)f2bf_rn(b.w);
    *(short4*)(dst + i) = s0;
    *(short4*)(dst + i + 4) = s1;
}

__global__ void k_zpad(short* __restrict__ Qtb, int HU, int MP) {
    int bi = blockIdx.x;
    int npad = MP - HU;
    int b = bi / npad, r = bi - b * npad;
    short4 z = {0, 0, 0, 0};
    *(short4*)(Qtb + ((size_t)b * MP + HU + r) * D_ + threadIdx.x * 4) = z;
}

// ---------------- fp32 tiled projection ----------------
__global__ __launch_bounds__(256) void k_proj(const float* __restrict__ A,
                                              const float* __restrict__ W,
                                              const float* __restrict__ bias,
                                              float* __restrict__ C, int M) {
    __shared__ float As[32][64 + 4];
    __shared__ float Bs[32][64 + 4];
    int m0 = blockIdx.x * 64, n0 = blockIdx.y * 64;
    int tid = threadIdx.x;
    int lr = tid >> 3;
    int lc = (tid & 7) * 4;
    int ty = tid >> 4, tx = tid & 15;
    float acc[4][4] = {{0.f}};
    for (int k0 = 0; k0 < D_; k0 += 32) {
#pragma unroll
        for (int half = 0; half < 2; ++half) {
            int r = lr + half * 32;
            int gm = m0 + r;
            float4 v = make_float4(0.f, 0.f, 0.f, 0.f);
            if (gm < M) v = *(const float4*)(A + (size_t)gm * D_ + k0 + lc);
            As[lc + 0][r] = v.x; As[lc + 1][r] = v.y; As[lc + 2][r] = v.z; As[lc + 3][r] = v.w;
            int gn = n0 + r;
            float4 w = *(const float4*)(W + (size_t)gn * D_ + k0 + lc);
            Bs[lc + 0][r] = w.x; Bs[lc + 1][r] = w.y; Bs[lc + 2][r] = w.z; Bs[lc + 3][r] = w.w;
        }
        __syncthreads();
#pragma unroll
        for (int kk = 0; kk < 32; ++kk) {
            float4 a = *(const float4*)&As[kk][ty * 4];
            float4 bb = *(const float4*)&Bs[kk][tx * 4];
            acc[0][0] += a.x * bb.x; acc[0][1] += a.x * bb.y; acc[0][2] += a.x * bb.z; acc[0][3] += a.x * bb.w;
            acc[1][0] += a.y * bb.x; acc[1][1] += a.y * bb.y; acc[1][2] += a.y * bb.z; acc[1][3] += a.y * bb.w;
            acc[2][0] += a.z * bb.x; acc[2][1] += a.z * bb.y; acc[2][2] += a.z * bb.z; acc[2][3] += a.z * bb.w;
            acc[3][0] += a.w * bb.x; acc[3][1] += a.w * bb.y; acc[3][2] += a.w * bb.z; acc[3][3] += a.w * bb.w;
        }
        __syncthreads();
    }
#pragma unroll
    for (int i = 0; i < 4; ++i) {
        int gm = m0 + ty * 4 + i;
        if (gm < M) {
            int gn = n0 + tx * 4;
            float4 v = make_float4(acc[i][0], acc[i][1], acc[i][2], acc[i][3]);
            if (bias) {
                v.x += bias[gn + 0]; v.y += bias[gn + 1];
                v.z += bias[gn + 2]; v.w += bias[gn + 3];
            }
            *(float4*)(C + (size_t)gm * D_ + gn) = v;
        }
    }
}

// ---------------- per-head Qt GEMM (writes bf16, 0.125-scaled) ----------------
__global__ __launch_bounds__(256) void k_qth(const float* __restrict__ Qs,
                                             const float* __restrict__ Wk,
                                             short* __restrict__ Qtb, int U, int MP) {
    __shared__ float As[32][64 + 4];
    __shared__ float Bs[32][64 + 4];
    int h = blockIdx.z;
    int m0 = blockIdx.x * 64, n0 = blockIdx.y * 64;
    int BU = B_ * U;
    int tid = threadIdx.x;
    int lr = tid >> 3, lc = (tid & 7) * 4;
    int ty = tid >> 4, tx = tid & 15;
    float acc[4][4] = {{0.f}};
    for (int k0 = 0; k0 < DH_; k0 += 32) {
#pragma unroll
        for (int half = 0; half < 2; ++half) {
            int r = lr + half * 32;
            int gm = m0 + r;
            float4 v = make_float4(0.f, 0.f, 0.f, 0.f);
            if (gm < BU) v = *(const float4*)(Qs + (size_t)gm * D_ + h * DH_ + k0 + lc);
            As[lc + 0][r] = v.x; As[lc + 1][r] = v.y; As[lc + 2][r] = v.z; As[lc + 3][r] = v.w;
            int kr = (tid >> 4) + half * 16;
            int nc = (tid & 15) * 4;
            float4 w = *(const float4*)(Wk + ((size_t)(h * DH_ + k0 + kr)) * D_ + n0 + nc);
            *(float4*)&Bs[kr][nc] = w;
        }
        __syncthreads();
#pragma unroll
        for (int kk = 0; kk < 32; ++kk) {
            float4 a = *(const float4*)&As[kk][ty * 4];
            float4 bb = *(const float4*)&Bs[kk][tx * 4];
            acc[0][0] += a.x * bb.x; acc[0][1] += a.x * bb.y; acc[0][2] += a.x * bb.z; acc[0][3] += a.x * bb.w;
            acc[1][0] += a.y * bb.x; acc[1][1] += a.y * bb.y; acc[1][2] += a.y * bb.z; acc[1][3] += a.y * bb.w;
            acc[2][0] += a.z * bb.x; acc[2][1] += a.z * bb.y; acc[2][2] += a.z * bb.z; acc[2][3] += a.z * bb.w;
            acc[3][0] += a.w * bb.x; acc[3][1] += a.w * bb.y; acc[3][2] += a.w * bb.z; acc[3][3] += a.w * bb.w;
        }
        __syncthreads();
    }
#pragma unroll
    for (int i = 0; i < 4; ++i) {
        int gm = m0 + ty * 4 + i;
        if (gm < BU) {
            int b = gm / U, ii = gm - b * U;
            short4 s;
            s.x = (short)f2bf_rn(0.125f * acc[i][0]);
            s.y = (short)f2bf_rn(0.125f * acc[i][1]);
            s.z = (short)f2bf_rn(0.125f * acc[i][2]);
            s.w = (short)f2bf_rn(0.125f * acc[i][3]);
            *(short4*)(Qtb + ((size_t)b * MP + h * U + ii) * D_ + n0 + tx * 4) = s;
        }
    }
}

// ================= 256x256 bf16 MFMA core (round-1 version: BK=64, 2-phase, counted vmcnt) ====
// 512 threads = 8 waves (2M x 4N), per-wave C = 128x64 (acc[8][4]).
// LDS: 2 buffers x (A 256x64 + B 256x64) bf16 = 128 KiB.
// Swizzle: 16B-slot index ^= (row & 7) on BOTH the global source (stage) and the
// ds_read address (rule #21: linear LDS dest for global_load_lds).
#define GEMM_NT 16   // K = 1024 / BK = 64

__device__ __forceinline__ void stage64(const short* __restrict__ Ag,
                                        const short* __restrict__ Bg,
                                        short* lA, short* lB, int kt, int tid) {
#pragma unroll
    for (int i = 0; i < 4; ++i) {
        int li = i * 512 + tid;
        int row = li >> 3, sl = li & 7;
        int off = row * D_ + kt + ((sl ^ (row & 7)) << 3);
        async_load16(Ag + off, lA + li * 8);
        async_load16(Bg + off, lB + li * 8);
    }
}

__device__ __forceinline__ bf8 lds_frag(const short* l, int R, int slot) {
    return *(const bf8*)(l + R * 64 + (((slot) ^ (R & 7)) << 3));
}

__device__ __forceinline__ void gemm256_core(const short* __restrict__ Ag,
                                             const short* __restrict__ Bg,
                                             short* lA0, short* lB0,
                                             f32x4 (&acc)[8][4]) {
    int tid = threadIdx.x;
    int lane = tid & 63, w = tid >> 6;
    int wr = w >> 2, wc = w & 3;
    int ln = lane & 15, q = lane >> 4;
#pragma unroll
    for (int mi = 0; mi < 8; ++mi)
#pragma unroll
        for (int ni = 0; ni < 4; ++ni)
            acc[mi][ni] = (f32x4){0.f, 0.f, 0.f, 0.f};

    stage64(Ag, Bg, lA0, lB0, 0, tid);
    stage64(Ag, Bg, lA0 + 16384, lB0 + 16384, 64, tid);

#pragma unroll 1
    for (int t = 0; t < GEMM_NT; ++t) {
        const int p = t & 1;
        short* lA = lA0 + p * 16384;
        short* lB = lB0 + p * 16384;
        if (t < GEMM_NT - 1) asm volatile("s_waitcnt vmcnt(8)" ::: "memory");
        else                 asm volatile("s_waitcnt vmcnt(0)" ::: "memory");
        __builtin_amdgcn_s_barrier();

        bf8 bfrag[4][2], afrag[4][2];
#pragma unroll
        for (int ni = 0; ni < 4; ++ni)
#pragma unroll
            for (int kh = 0; kh < 2; ++kh)
                bfrag[ni][kh] = lds_frag(lB, wc * 64 + ni * 16 + ln, kh * 4 + q);
#pragma unroll
        for (int mi = 0; mi < 4; ++mi)
#pragma unroll
            for (int kh = 0; kh < 2; ++kh)
                afrag[mi][kh] = lds_frag(lA, wr * 128 + mi * 16 + ln, kh * 4 + q);
        __builtin_amdgcn_s_setprio(1);
#pragma unroll
        for (int kh = 0; kh < 2; ++kh)
#pragma unroll
            for (int mi = 0; mi < 4; ++mi)
#pragma unroll
                for (int ni = 0; ni < 4; ++ni)
                    acc[mi][ni] = __builtin_amdgcn_mfma_f32_16x16x32_bf16(
                        afrag[mi][kh], bfrag[ni][kh], acc[mi][ni], 0, 0, 0);
        __builtin_amdgcn_s_setprio(0);
#pragma unroll
        for (int mi = 0; mi < 4; ++mi)
#pragma unroll
            for (int kh = 0; kh < 2; ++kh)
                afrag[mi][kh] = lds_frag(lA, wr * 128 + 64 + mi * 16 + ln, kh * 4 + q);
        __builtin_amdgcn_s_setprio(1);
#pragma unroll
        for (int kh = 0; kh < 2; ++kh)
#pragma unroll
            for (int mi = 0; mi < 4; ++mi)
#pragma unroll
                for (int ni = 0; ni < 4; ++ni)
                    acc[4 + mi][ni] = __builtin_amdgcn_mfma_f32_16x16x32_bf16(
                        afrag[mi][kh], bfrag[ni][kh], acc[4 + mi][ni], 0, 0, 0);
        __builtin_amdgcn_s_setprio(0);
        asm volatile("" ::: "memory");
        __builtin_amdgcn_s_barrier();   // all waves done reading buf p -> safe to overwrite
        if (t + 2 < GEMM_NT)
            stage64(Ag, Bg, lA, lB, (t + 2) * 64, tid);
    }
}

// ---------------- scores GEMM + fused exp (256x256 core) ----------------
__global__ __launch_bounds__(512, 2) void k_scores2(const short* __restrict__ Qtb,
                                                    const short* __restrict__ xb,
                                                    short* __restrict__ attnb, int MP) {
    __shared__ short lA[2][16384];
    __shared__ short lB[2][16384];
    int bid = blockIdx.x;
    int lg = (bid & 7) * (gridDim.x >> 3) + (bid >> 3);   // bijective XCD swizzle
    int MT = MP >> 8;                  // 256-row m-tiles (MP=768 -> 3)
    int per_b = MT << 4;               // 16 n-tiles
    int b = lg / per_b;
    int r = lg - b * per_b;
    int mt = r >> 4, nt = r & 15;
    const short* Ag = Qtb + ((size_t)b * MP + mt * 256) * D_;
    const short* Bg = xb + ((size_t)b * T_ + nt * 256) * D_;
    f32x4 acc[8][4];
    gemm256_core(Ag, Bg, &lA[0][0], &lB[0][0], acc);

    short* Cb = attnb + (size_t)b * MP * T_;
    int tid = threadIdx.x;
    int lane = tid & 63, w = tid >> 6;
    int wr = w >> 2, wc = w & 3;
    int ln = lane & 15, q = lane >> 4;
    int row0 = mt * 256 + wr * 128;
    int col0 = nt * 256 + wc * 64;
#pragma unroll
    for (int mi = 0; mi < 8; ++mi)
#pragma unroll
        for (int ni = 0; ni < 4; ++ni) {
            int col = col0 + ni * 16 + ln;
#pragma unroll
            for (int rr = 0; rr < 4; ++rr) {
                int grow = row0 + mi * 16 + q * 4 + rr;
                Cb[(size_t)grow * T_ + col] = (short)f2bf_rn(__expf(acc[mi][ni][rr]));
            }
        }
}

// ---------------- V GEMM (256x256 core) + transpose epilogue to Vt[(b*H+h)*64+dh][t] ----------------
__global__ __launch_bounds__(512, 2) void k_v2(const short* __restrict__ xb,
                                               const short* __restrict__ Wvb,
                                               short* __restrict__ Vt) {
    __shared__ short lA[2][16384];
    __shared__ short lB[2][16384];
    int bid = blockIdx.x;
    int lg = (bid & 7) * (gridDim.x >> 3) + (bid >> 3);   // 512 blocks, 64/XCD
    int mt = lg >> 2, nt = lg & 3;     // mt: 128 t-tiles, nt: 4 head-group tiles
    const short* Ag = xb + (size_t)mt * 256 * D_;
    const short* Bg = Wvb + (size_t)nt * 256 * D_;
    f32x4 acc[8][4];
    gemm256_core(Ag, Bg, &lA[0][0], &lB[0][0], acc);

    // epilogue: per-wave transpose (t, dh) -> (dh, t) via LDS, 4 passes of 16 dh
    int tid = threadIdx.x;
    int lane = tid & 63, w = tid >> 6;
    int wr = w >> 2, wc = w & 3;
    int ln = lane & 15, q = lane >> 4;
    int h = nt * 4 + wc;               // this wave owns one full head
    int b = mt >> 4;
    int tIn = (mt & 15) * 256 + wr * 128;
    const int PITCH = 136;             // shorts per dh row (128 t + pad)
    short* ep = &lA[0][0] + w * 2304;  // 2176 needed, 2304 alloc'd per wave
    size_t vbase = ((size_t)(b * H_ + h) * DH_) * T_;
#pragma unroll
    for (int ni = 0; ni < 4; ++ni) {
#pragma unroll
        for (int mi = 0; mi < 8; ++mi) {
            short4 s;
            s.x = (short)f2bf_rn(acc[mi][ni][0]);
            s.y = (short)f2bf_rn(acc[mi][ni][1]);
            s.z = (short)f2bf_rn(acc[mi][ni][2]);
            s.w = (short)f2bf_rn(acc[mi][ni][3]);
            *(short4*)(ep + ln * PITCH + mi * 16 + q * 4) = s;
        }
        __syncthreads();
#pragma unroll
        for (int it = 0; it < 2; ++it) {
            int dhl = it * 8 + (lane >> 3);
            int seg = lane & 7;
            bf8 v0 = *(const bf8*)(ep + dhl * PITCH + seg * 8);
            bf8 v1 = *(const bf8*)(ep + dhl * PITCH + (seg + 8) * 8);
            int dh = ni * 16 + dhl;
            *(bf8*)(Vt + vbase + (size_t)dh * T_ + tIn + seg * 8) = v0;
            *(bf8*)(Vt + vbase + (size_t)dh * T_ + tIn + 64 + seg * 8) = v1;
        }
        __syncthreads();
    }
}

// ---------------- PV flash: O_partial, rs_partial per (b,h,chunk) ----------------
// A-tile (48 x 128) now staged in LDS once per t-tile: kills the 4x-redundant
// scattered global reads of attnb (200 MB -> 50 MB for the whole kernel).
__global__ __launch_bounds__(256) void k_pv(const short* __restrict__ attnb,
                                            const short* __restrict__ Vt,
                                            float* __restrict__ Op,
                                            float* __restrict__ rsp,
                                            int U, int MP) {
    __shared__ short vt[64 * 136];         // V^T tile (dh, t), 17408 B
    __shared__ short at[48 * 136];         // A tile (row, t), 13056 B
    int gid = blockIdx.x;
    int c = gid & (NC_ - 1);
    int bh = gid >> 2;
    int h = bh & (H_ - 1);
    int b = bh >> 4;
    int tid = threadIdx.x;
    int lane = tid & 63, w = tid >> 6;
    int quad = lane >> 4;
    const short* Arow = attnb + ((size_t)b * MP + h * U) * T_;
    const short* Vrow = Vt + (size_t)bh * DH_ * T_;

    f32x4 O[3];
#pragma unroll
    for (int mi = 0; mi < 3; ++mi) O[mi] = (f32x4){0.f, 0.f, 0.f, 0.f};
    float rs[3] = {0.f, 0.f, 0.f};

    for (int tt = 0; tt < (T_ / NC_) / 128; ++tt) {
        int t0 = c * (T_ / NC_) + tt * 128;
        // stage V^T tile (64 dh x 128 t)
#pragma unroll
        for (int it = 0; it < 4; ++it) {
            int idx = it * 256 + tid;
            int dh = idx >> 4, seg = idx & 15;
            bf8 v = *(const bf8*)(Vrow + (size_t)dh * T_ + t0 + seg * 8);
            *(bf8*)(vt + dh * 136 + seg * 8) = v;
        }
        // stage A tile (48 rows x 128 t), coalesced 128B rows
#pragma unroll
        for (int it = 0; it < 3; ++it) {
            int idx = it * 256 + tid;
            int r = idx >> 4, seg = idx & 15;
            bf8 v = *(const bf8*)(Arow + (size_t)r * T_ + t0 + seg * 8);
            *(bf8*)(at + r * 136 + seg * 8) = v;
        }
        __syncthreads();
        bf8 af[3][4];
#pragma unroll
        for (int mi = 0; mi < 3; ++mi)
#pragma unroll
            for (int kf = 0; kf < 4; ++kf)
                af[mi][kf] = *(const bf8*)(at + (mi * 16 + (lane & 15)) * 136 + kf * 32 + quad * 8);
        if (w == 0) {
#pragma unroll
            for (int mi = 0; mi < 3; ++mi)
#pragma unroll
                for (int kf = 0; kf < 4; ++kf)
#pragma unroll
                    for (int j = 0; j < 8; ++j) rs[mi] += (float)af[mi][kf][j];
        }
#pragma unroll
        for (int kf = 0; kf < 4; ++kf) {
            bf8 bfr = *(const bf8*)(vt + (w * 16 + (lane & 15)) * 136 + kf * 32 + quad * 8);
#pragma unroll
            for (int mi = 0; mi < 3; ++mi)
                O[mi] = __builtin_amdgcn_mfma_f32_16x16x32_bf16(af[mi][kf], bfr, O[mi], 0, 0, 0);
        }
        __syncthreads();
    }
#pragma unroll
    for (int mi = 0; mi < 3; ++mi)
#pragma unroll
        for (int r = 0; r < 4; ++r)
            Op[((size_t)gid * 48 + mi * 16 + quad * 4 + r) * DH_ + w * 16 + (lane & 15)] = O[mi][r];
    if (w == 0) {
#pragma unroll
        for (int mi = 0; mi < 3; ++mi) {
            rs[mi] += __shfl_xor(rs[mi], 16);
            rs[mi] += __shfl_xor(rs[mi], 32);
            if (quad == 0) rsp[(size_t)gid * 48 + mi * 16 + lane] = rs[mi];
        }
    }
}

// ---------------- reduce chunks, normalize, assemble R ----------------
__global__ __launch_bounds__(256) void k_rows2(const float* __restrict__ Op,
                                               const float* __restrict__ rsp,
                                               float* __restrict__ R, int U) {
    __shared__ float inv[48];
    __shared__ float msum[4][64];
    int bh = blockIdx.x;
    int b = bh >> 4, h = bh & (H_ - 1);
    int tid = threadIdx.x;
    if (tid < 48) {
        float s = 0.f;
        for (int cc = 0; cc < NC_; ++cc) s += rsp[(size_t)(bh * NC_ + cc) * 48 + tid];
        inv[tid] = 1.f / s;
    }
    __syncthreads();
    int dh = tid & 63, ig = tid >> 6;
    float acc = 0.f;
    for (int p = 0; p < 11; ++p) {
        int i = p * 4 + ig;
        if (i < U) {
            float o = 0.f;
            for (int cc = 0; cc < NC_; ++cc)
                o += Op[((size_t)(bh * NC_ + cc) * 48 + i) * DH_ + dh];
            float v = o * inv[i];
            R[((size_t)b * (U + 1) + 1 + i) * D_ + h * DH_ + dh] = v;
            acc += v;
        }
    }
    msum[ig][dh] = acc;
    __syncthreads();
    if (ig == 0)
        R[((size_t)b * (U + 1)) * D_ + h * DH_ + dh] =
            (msum[0][dh] + msum[1][dh] + msum[2][dh] + msum[3][dh]) / (float)U;
}

__global__ __launch_bounds__(256) void k_fill(const float* __restrict__ Yr,
                                              const int* __restrict__ sel,
                                              float* __restrict__ y, int U) {
    int blk = blockIdx.x;
    int b = blk >> 12, t = blk & (T_ - 1);
    int j = sel[t];
    const float4* src = (const float4*)(Yr + ((size_t)b * (U + 1) + j) * D_);
    float4* dst = (float4*)(y + (size_t)blk * D_);
    dst[threadIdx.x] = src[threadIdx.x];
}

extern "C" void kernel_launch(void* const* d_in, const int* in_sizes, int n_in,
                              void* d_out, int out_size, void* d_ws, size_t ws_size,
                              hipStream_t stream) {
    const float* x  = (const float*)d_in[0];
    const float* Wq = (const float*)d_in[1];
    const float* Wk = (const float*)d_in[2];
    const float* Wv = (const float*)d_in[3];
    const float* Wo = (const float*)d_in[4];
    const float* bo = (const float*)d_in[5];
    const int*  idx = (const int*)d_in[6];
    int U = in_sizes[6];                      // 41
    int HU = H_ * U;                          // 656
    int MP = ((HU + 127) / 128) * 128;        // 768

    char* w = (char*)d_ws;
    auto alloc = [&](size_t bytes) { char* p = w; w += (bytes + 255) & ~(size_t)255; return p; };

    float* xs    = (float*)alloc((size_t)B_ * U * D_ * 4);
    float* Qs    = (float*)alloc((size_t)B_ * U * D_ * 4);
    short* Qtb   = (short*)alloc((size_t)B_ * MP * D_ * 2);
    short* xb    = (short*)alloc((size_t)B_ * T_ * D_ * 2);
    short* Wvb   = (short*)alloc((size_t)D_ * D_ * 2);
    short* attnb = (short*)alloc((size_t)B_ * MP * T_ * 2);
    short* Vtb   = (short*)alloc((size_t)B_ * D_ * T_ * 2);
    float* Opb   = (float*)alloc((size_t)B_ * H_ * NC_ * 48 * DH_ * 4);
    float* rspb  = (float*)alloc((size_t)B_ * H_ * NC_ * 48 * 4);
    float* R     = (float*)alloc((size_t)B_ * (U + 1) * D_ * 4);
    float* Yr    = (float*)alloc((size_t)B_ * (U + 1) * D_ * 4);
    int*   sel   = (int*)alloc((size_t)T_ * 4);

    int MT = MP / 256;                        // 3

    k_sel<<<dim3(1), dim3(256), 0, stream>>>(idx, sel, U);
    k_gather<<<dim3(B_ * U), dim3(256), 0, stream>>>(x, idx, xs, U);
    k_proj<<<dim3((B_ * U + 63) / 64, D_ / 64), dim3(256), 0, stream>>>(xs, Wq, nullptr, Qs, B_ * U);
    k_cvt_flat<<<dim3((size_t)B_ * T_ * D_ / 2048), dim3(256), 0, stream>>>(x, xb);
    k_cvt_flat<<<dim3((size_t)D_ * D_ / 2048), dim3(256), 0, stream>>>(Wv, Wvb);
    k_zpad<<<dim3(B_ * (MP - HU)), dim3(256), 0, stream>>>(Qtb, HU, MP);
    k_qth<<<dim3((B_ * U + 63) / 64, D_ / 64, H_), dim3(256), 0, stream>>>(Qs, Wk, Qtb, U, MP);
    k_scores2<<<dim3(B_ * MT * 16), dim3(512), 0, stream>>>(Qtb, xb, attnb, MP);
    k_v2<<<dim3((B_ * T_ / 256) * (D_ / 256)), dim3(512), 0, stream>>>(xb, Wvb, Vtb);
    k_pv<<<dim3(B_ * H_ * NC_), dim3(256), 0, stream>>>(attnb, Vtb, Opb, rspb, U, MP);
    k_rows2<<<dim3(B_ * H_), dim3(256), 0, stream>>>(Opb, rspb, R, U);
    k_proj<<<dim3((B_ * (U + 1) + 63) / 64, D_ / 64), dim3(256), 0, stream>>>(R, Wo, bo, Yr, B_ * (U + 1));
    k_fill<<<dim3(B_ * T_), dim3(256), 0, stream>>>(Yr, sel, (float*)d_out, U);
}

// Round 5
// 566.768 us; speedup vs baseline: 1.0943x; 1.0220x over previous
//
#include <hip/hip_runtime.h>
#include <hip/hip_bf16.h>

#define B_  8
#define T_  4096
#define D_  1024
#define H_  16
#define DH_ 64
#define NC_ 4          // T-chunks in k_pv

typedef __bf16 bf8 __attribute__((ext_vector_type(8)));
typedef float f32x4 __attribute__((ext_vector_type(4)));

__device__ __forceinline__ unsigned short f2bf_rn(float f) {
    unsigned u = __float_as_uint(f);
    unsigned r = (u + 0x7FFF + ((u >> 16) & 1)) >> 16;
    return (unsigned short)r;
}

__device__ __forceinline__ void async_load16(const void* gp, void* lp) {
    __builtin_amdgcn_global_load_lds(
        (const __attribute__((address_space(1))) unsigned*)(gp),
        (__attribute__((address_space(3))) unsigned*)(lp), 16, 0, 0);
}

// ---------------- small helpers ----------------

__global__ void k_sel(const int* __restrict__ idx, int* __restrict__ sel, int U) {
    for (int t = threadIdx.x; t < T_; t += 256) sel[t] = 0;
    __syncthreads();
    if (threadIdx.x < U) sel[idx[threadIdx.x]] = threadIdx.x + 1;
}

__global__ void k_gather(const float* __restrict__ x, const int* __restrict__ idx,
                         float* __restrict__ xs, int U) {
    int bi = blockIdx.x;
    int b = bi / U, i = bi - b * U;
    int t = idx[i];
    const float4* src = (const float4*)(x + ((size_t)(b * T_ + t)) * D_);
    float4* dst = (float4*)(xs + (size_t)bi * D_);
    dst[threadIdx.x] = src[threadIdx.x];
}

__global__ void k_cvt_flat(const float* __restrict__ src, short* __restrict__ dst) {
    size_t i = ((size_t)blockIdx.x * 256 + threadIdx.x) * 8;
    float4 a = *(const float4*)(src + i);
    float4 b = *(const float4*)(src + i + 4);
    short4 s0, s1;
    s0.x = (short)f2bf_rn(a.x); s0.y = (short)f2bf_rn(a.y);
    s0.z = (short)f2bf_rn(a.z); s0.w = (short)f2bf_rn(a.w);
    s1.x = (short)f2bf_rn(b.x); s1.y = (short)f2bf_rn(b.y);
    s1.z = (short)f2bf_rn(b.z); s1.w = (short)f2bf_rn(b.w);
    *(short4*)(dst + i) = s0;
    *(short4*)(dst + i + 4) = s1;
}

// ---------------- fp32 tiled projection ----------------
__global__ __launch_bounds__(256) void k_proj(const float* __restrict__ A,
                                              const float* __restrict__ W,
                                              const float* __restrict__ bias,
                                              float* __restrict__ C, int M) {
    __shared__ float As[32][64 + 4];
    __shared__ float Bs[32][64 + 4];
    int m0 = blockIdx.x * 64, n0 = blockIdx.y * 64;
    int tid = threadIdx.x;
    int lr = tid >> 3;
    int lc = (tid & 7) * 4;
    int ty = tid >> 4, tx = tid & 15;
    float acc[4][4] = {{0.f}};
    for (int k0 = 0; k0 < D_; k0 += 32) {
#pragma unroll
        for (int half = 0; half < 2; ++half) {
            int r = lr + half * 32;
            int gm = m0 + r;
            float4 v = make_float4(0.f, 0.f, 0.f, 0.f);
            if (gm < M) v = *(const float4*)(A + (size_t)gm * D_ + k0 + lc);
            As[lc + 0][r] = v.x; As[lc + 1][r] = v.y; As[lc + 2][r] = v.z; As[lc + 3][r] = v.w;
            int gn = n0 + r;
            float4 w = *(const float4*)(W + (size_t)gn * D_ + k0 + lc);
            Bs[lc + 0][r] = w.x; Bs[lc + 1][r] = w.y; Bs[lc + 2][r] = w.z; Bs[lc + 3][r] = w.w;
        }
        __syncthreads();
#pragma unroll
        for (int kk = 0; kk < 32; ++kk) {
            float4 a = *(const float4*)&As[kk][ty * 4];
            float4 bb = *(const float4*)&Bs[kk][tx * 4];
            acc[0][0] += a.x * bb.x; acc[0][1] += a.x * bb.y; acc[0][2] += a.x * bb.z; acc[0][3] += a.x * bb.w;
            acc[1][0] += a.y * bb.x; acc[1][1] += a.y * bb.y; acc[1][2] += a.y * bb.z; acc[1][3] += a.y * bb.w;
            acc[2][0] += a.z * bb.x; acc[2][1] += a.z * bb.y; acc[2][2] += a.z * bb.z; acc[2][3] += a.z * bb.w;
            acc[3][0] += a.w * bb.x; acc[3][1] += a.w * bb.y; acc[3][2] += a.w * bb.z; acc[3][3] += a.w * bb.w;
        }
        __syncthreads();
    }
#pragma unroll
    for (int i = 0; i < 4; ++i) {
        int gm = m0 + ty * 4 + i;
        if (gm < M) {
            int gn = n0 + tx * 4;
            float4 v = make_float4(acc[i][0], acc[i][1], acc[i][2], acc[i][3]);
            if (bias) {
                v.x += bias[gn + 0]; v.y += bias[gn + 1];
                v.z += bias[gn + 2]; v.w += bias[gn + 3];
            }
            *(float4*)(C + (size_t)gm * D_ + gn) = v;
        }
    }
}

// ---------------- per-head Qt GEMM (writes bf16, 0.125-scaled) ----------------
__global__ __launch_bounds__(256) void k_qth(const float* __restrict__ Qs,
                                             const float* __restrict__ Wk,
                                             short* __restrict__ Qtb, int U, int MP) {
    __shared__ float As[32][64 + 4];
    __shared__ float Bs[32][64 + 4];
    int h = blockIdx.z;
    int m0 = blockIdx.x * 64, n0 = blockIdx.y * 64;
    int BU = B_ * U;
    int tid = threadIdx.x;
    int lr = tid >> 3, lc = (tid & 7) * 4;
    int ty = tid >> 4, tx = tid & 15;
    float acc[4][4] = {{0.f}};
    for (int k0 = 0; k0 < DH_; k0 += 32) {
#pragma unroll
        for (int half = 0; half < 2; ++half) {
            int r = lr + half * 32;
            int gm = m0 + r;
            float4 v = make_float4(0.f, 0.f, 0.f, 0.f);
            if (gm < BU) v = *(const float4*)(Qs + (size_t)gm * D_ + h * DH_ + k0 + lc);
            As[lc + 0][r] = v.x; As[lc + 1][r] = v.y; As[lc + 2][r] = v.z; As[lc + 3][r] = v.w;
            int kr = (tid >> 4) + half * 16;
            int nc = (tid & 15) * 4;
            float4 w = *(const float4*)(Wk + ((size_t)(h * DH_ + k0 + kr)) * D_ + n0 + nc);
            *(float4*)&Bs[kr][nc] = w;
        }
        __syncthreads();
#pragma unroll
        for (int kk = 0; kk < 32; ++kk) {
            float4 a = *(const float4*)&As[kk][ty * 4];
            float4 bb = *(const float4*)&Bs[kk][tx * 4];
            acc[0][0] += a.x * bb.x; acc[0][1] += a.x * bb.y; acc[0][2] += a.x * bb.z; acc[0][3] += a.x * bb.w;
            acc[1][0] += a.y * bb.x; acc[1][1] += a.y * bb.y; acc[1][2] += a.y * bb.z; acc[1][3] += a.y * bb.w;
            acc[2][0] += a.z * bb.x; acc[2][1] += a.z * bb.y; acc[2][2] += a.z * bb.z; acc[2][3] += a.z * bb.w;
            acc[3][0] += a.w * bb.x; acc[3][1] += a.w * bb.y; acc[3][2] += a.w * bb.z; acc[3][3] += a.w * bb.w;
        }
        __syncthreads();
    }
#pragma unroll
    for (int i = 0; i < 4; ++i) {
        int gm = m0 + ty * 4 + i;
        if (gm < BU) {
            int b = gm / U, ii = gm - b * U;
            short4 s;
            s.x = (short)f2bf_rn(0.125f * acc[i][0]);
            s.y = (short)f2bf_rn(0.125f * acc[i][1]);
            s.z = (short)f2bf_rn(0.125f * acc[i][2]);
            s.w = (short)f2bf_rn(0.125f * acc[i][3]);
            *(short4*)(Qtb + ((size_t)b * MP + h * U + ii) * D_ + n0 + tx * 4) = s;
        }
    }
}

// ================= 256x256 bf16 MFMA core (round-3 known-good: BK=64, 2-phase, counted vmcnt) ====
// 512 threads = 8 waves (2M x 4N), per-wave C = 128x64 (acc[8][4] -> AGPRs).
// LDS: 2 buffers x (A 256x64 + B 256x64) bf16 = 128 KiB, 1 block/CU.
// NOTE: (512,2) launch bounds -> 256 unified regs/wave; ~100 VGPR + 128 AGPR fits.
// Do NOT raise min-waves: 2 blocks/CU needs <=128 regs and guarantees spill.
#define GEMM_NT 16   // K = 1024 / BK = 64

__device__ __forceinline__ void stage64(const short* __restrict__ Ag,
                                        const short* __restrict__ Bg,
                                        short* lA, short* lB, int kt, int tid) {
#pragma unroll
    for (int i = 0; i < 4; ++i) {
        int li = i * 512 + tid;
        int row = li >> 3, sl = li & 7;
        int off = row * D_ + kt + ((sl ^ (row & 7)) << 3);
        async_load16(Ag + off, lA + li * 8);
        async_load16(Bg + off, lB + li * 8);
    }
}

__device__ __forceinline__ bf8 lds_frag(const short* l, int R, int slot) {
    return *(const bf8*)(l + R * 64 + (((slot) ^ (R & 7)) << 3));
}

__device__ __forceinline__ void gemm256_core(const short* __restrict__ Ag,
                                             const short* __restrict__ Bg,
                                             short* lA0, short* lB0,
                                             f32x4 (&acc)[8][4]) {
    int tid = threadIdx.x;
    int lane = tid & 63, w = tid >> 6;
    int wr = w >> 2, wc = w & 3;
    int ln = lane & 15, q = lane >> 4;
#pragma unroll
    for (int mi = 0; mi < 8; ++mi)
#pragma unroll
        for (int ni = 0; ni < 4; ++ni)
            acc[mi][ni] = (f32x4){0.f, 0.f, 0.f, 0.f};

    stage64(Ag, Bg, lA0, lB0, 0, tid);
    stage64(Ag, Bg, lA0 + 16384, lB0 + 16384, 64, tid);

#pragma unroll 1
    for (int t = 0; t < GEMM_NT; ++t) {
        const int p = t & 1;
        short* lA = lA0 + p * 16384;
        short* lB = lB0 + p * 16384;
        if (t < GEMM_NT - 1) asm volatile("s_waitcnt vmcnt(8)" ::: "memory");
        else                 asm volatile("s_waitcnt vmcnt(0)" ::: "memory");
        __builtin_amdgcn_s_barrier();

        bf8 bfrag[4][2], afrag[4][2];
#pragma unroll
        for (int ni = 0; ni < 4; ++ni)
#pragma unroll
            for (int kh = 0; kh < 2; ++kh)
                bfrag[ni][kh] = lds_frag(lB, wc * 64 + ni * 16 + ln, kh * 4 + q);
#pragma unroll
        for (int mi = 0; mi < 4; ++mi)
#pragma unroll
            for (int kh = 0; kh < 2; ++kh)
                afrag[mi][kh] = lds_frag(lA, wr * 128 + mi * 16 + ln, kh * 4 + q);
        __builtin_amdgcn_s_setprio(1);
#pragma unroll
        for (int kh = 0; kh < 2; ++kh)
#pragma unroll
            for (int mi = 0; mi < 4; ++mi)
#pragma unroll
                for (int ni = 0; ni < 4; ++ni)
                    acc[mi][ni] = __builtin_amdgcn_mfma_f32_16x16x32_bf16(
                        afrag[mi][kh], bfrag[ni][kh], acc[mi][ni], 0, 0, 0);
        __builtin_amdgcn_s_setprio(0);
#pragma unroll
        for (int mi = 0; mi < 4; ++mi)
#pragma unroll
            for (int kh = 0; kh < 2; ++kh)
                afrag[mi][kh] = lds_frag(lA, wr * 128 + 64 + mi * 16 + ln, kh * 4 + q);
        __builtin_amdgcn_s_setprio(1);
#pragma unroll
        for (int kh = 0; kh < 2; ++kh)
#pragma unroll
            for (int mi = 0; mi < 4; ++mi)
#pragma unroll
                for (int ni = 0; ni < 4; ++ni)
                    acc[4 + mi][ni] = __builtin_amdgcn_mfma_f32_16x16x32_bf16(
                        afrag[mi][kh], bfrag[ni][kh], acc[4 + mi][ni], 0, 0, 0);
        __builtin_amdgcn_s_setprio(0);
        asm volatile("" ::: "memory");
        __builtin_amdgcn_s_barrier();   // all waves done reading buf p -> safe to overwrite
        if (t + 2 < GEMM_NT)
            stage64(Ag, Bg, lA, lB, (t + 2) * 64, tid);
    }
}

// ---------------- merged GEMM launch: V-blocks (lg<512) + scores-blocks (lg>=512) ----------------
// 896 blocks (%8==0 -> bijective XCD swizzle). Packing the 384 scores-blocks behind the
// 512 V-blocks removes the scores grid's half-empty second block-round (tail waste
// 0.5/1.5 rounds -> 0.5/3.5 rounds at 256 blocks/round).
__global__ __launch_bounds__(512, 2) void k_gemm(const short* __restrict__ Qtb,
                                                 const short* __restrict__ xb,
                                                 const short* __restrict__ Wvb,
                                                 short* __restrict__ attnb,
                                                 short* __restrict__ Vt, int MP) {
    __shared__ short lAB[4][16384];      // 128 KiB: [0..1]=A dbuf, [2..3]=B dbuf
    int bid = blockIdx.x;
    int cpx = gridDim.x >> 3;
    int lg = (bid & 7) * cpx + (bid >> 3);
    int tid = threadIdx.x;
    int lane = tid & 63, w = tid >> 6;
    int wr = w >> 2, wc = w & 3;
    int ln = lane & 15, q = lane >> 4;
    f32x4 acc[8][4];

    if (lg < 512) {
        // ---- V GEMM: Vt[(b*H+h)*64+dh][t] ----
        int mt = lg >> 2, nt = lg & 3;
        gemm256_core(xb + (size_t)mt * 256 * D_, Wvb + (size_t)nt * 256 * D_,
                     &lAB[0][0], &lAB[2][0], acc);
        // transpose epilogue (t, dh) -> (dh, t) via LDS, 4 passes of 16 dh
        int h = nt * 4 + wc;
        int b = mt >> 4;
        int tIn = (mt & 15) * 256 + wr * 128;
        const int PITCH = 136;
        short* ep = &lAB[0][0] + w * 2304;
        size_t vbase = ((size_t)(b * H_ + h) * DH_) * T_;
#pragma unroll
        for (int ni = 0; ni < 4; ++ni) {
#pragma unroll
            for (int mi = 0; mi < 8; ++mi) {
                short4 s;
                s.x = (short)f2bf_rn(acc[mi][ni][0]);
                s.y = (short)f2bf_rn(acc[mi][ni][1]);
                s.z = (short)f2bf_rn(acc[mi][ni][2]);
                s.w = (short)f2bf_rn(acc[mi][ni][3]);
                *(short4*)(ep + ln * PITCH + mi * 16 + q * 4) = s;
            }
            __syncthreads();
#pragma unroll
            for (int it = 0; it < 2; ++it) {
                int dhl = it * 8 + (lane >> 3);
                int seg = lane & 7;
                bf8 v0 = *(const bf8*)(ep + dhl * PITCH + seg * 8);
                bf8 v1 = *(const bf8*)(ep + dhl * PITCH + (seg + 8) * 8);
                int dh = ni * 16 + dhl;
                *(bf8*)(Vt + vbase + (size_t)dh * T_ + tIn + seg * 8) = v0;
                *(bf8*)(Vt + vbase + (size_t)dh * T_ + tIn + 64 + seg * 8) = v1;
            }
            __syncthreads();
        }
    } else {
        // ---- scores GEMM + fused exp ----
        int r2 = lg - 512;                 // 0..383
        int b = r2 / 48;                   // 48 = 3 m-tiles x 16 n-tiles
        int rr = r2 - b * 48;
        int mt = rr >> 4, nt = rr & 15;
        gemm256_core(Qtb + ((size_t)b * MP + mt * 256) * D_,
                     xb + ((size_t)b * T_ + nt * 256) * D_,
                     &lAB[0][0], &lAB[2][0], acc);
        short* Cb = attnb + (size_t)b * MP * T_;
        int row0 = mt * 256 + wr * 128;
        int col0 = nt * 256 + wc * 64;
#pragma unroll
        for (int mi = 0; mi < 8; ++mi)
#pragma unroll
            for (int ni = 0; ni < 4; ++ni) {
                int col = col0 + ni * 16 + ln;
#pragma unroll
                for (int rr2 = 0; rr2 < 4; ++rr2) {
                    int grow = row0 + mi * 16 + q * 4 + rr2;
                    Cb[(size_t)grow * T_ + col] = (short)f2bf_rn(__expf(acc[mi][ni][rr2]));
                }
            }
    }
}

// ---------------- PV flash: O_partial, rs_partial per (b,h,chunk) ----------------
__global__ __launch_bounds__(256) void k_pv(const short* __restrict__ attnb,
                                            const short* __restrict__ Vt,
                                            float* __restrict__ Op,
                                            float* __restrict__ rsp,
                                            int U, int MP) {
    __shared__ short vt[64 * 136];         // V^T tile (dh, t)
    __shared__ short at[48 * 136];         // A tile (row, t)
    int gid = blockIdx.x;
    int c = gid & (NC_ - 1);
    int bh = gid >> 2;
    int h = bh & (H_ - 1);
    int b = bh >> 4;
    int tid = threadIdx.x;
    int lane = tid & 63, w = tid >> 6;
    int quad = lane >> 4;
    const short* Arow = attnb + ((size_t)b * MP + h * U) * T_;
    const short* Vrow = Vt + (size_t)bh * DH_ * T_;

    f32x4 O[3];
#pragma unroll
    for (int mi = 0; mi < 3; ++mi) O[mi] = (f32x4){0.f, 0.f, 0.f, 0.f};
    float rs[3] = {0.f, 0.f, 0.f};

    for (int tt = 0; tt < (T_ / NC_) / 128; ++tt) {
        int t0 = c * (T_ / NC_) + tt * 128;
#pragma unroll
        for (int it = 0; it < 4; ++it) {
            int idx = it * 256 + tid;
            int dh = idx >> 4, seg = idx & 15;
            bf8 v = *(const bf8*)(Vrow + (size_t)dh * T_ + t0 + seg * 8);
            *(bf8*)(vt + dh * 136 + seg * 8) = v;
        }
#pragma unroll
        for (int it = 0; it < 3; ++it) {
            int idx = it * 256 + tid;
            int r = idx >> 4, seg = idx & 15;
            bf8 v = *(const bf8*)(Arow + (size_t)r * T_ + t0 + seg * 8);
            *(bf8*)(at + r * 136 + seg * 8) = v;
        }
        __syncthreads();
        bf8 af[3][4];
#pragma unroll
        for (int mi = 0; mi < 3; ++mi)
#pragma unroll
            for (int kf = 0; kf < 4; ++kf)
                af[mi][kf] = *(const bf8*)(at + (mi * 16 + (lane & 15)) * 136 + kf * 32 + quad * 8);
        if (w == 0) {
#pragma unroll
            for (int mi = 0; mi < 3; ++mi)
#pragma unroll
                for (int kf = 0; kf < 4; ++kf)
#pragma unroll
                    for (int j = 0; j < 8; ++j) rs[mi] += (float)af[mi][kf][j];
        }
#pragma unroll
        for (int kf = 0; kf < 4; ++kf) {
            bf8 bfr = *(const bf8*)(vt + (w * 16 + (lane & 15)) * 136 + kf * 32 + quad * 8);
#pragma unroll
            for (int mi = 0; mi < 3; ++mi)
                O[mi] = __builtin_amdgcn_mfma_f32_16x16x32_bf16(af[mi][kf], bfr, O[mi], 0, 0, 0);
        }
        __syncthreads();
    }
#pragma unroll
    for (int mi = 0; mi < 3; ++mi)
#pragma unroll
        for (int r = 0; r < 4; ++r)
            Op[((size_t)gid * 48 + mi * 16 + quad * 4 + r) * DH_ + w * 16 + (lane & 15)] = O[mi][r];
    if (w == 0) {
#pragma unroll
        for (int mi = 0; mi < 3; ++mi) {
            rs[mi] += __shfl_xor(rs[mi], 16);
            rs[mi] += __shfl_xor(rs[mi], 32);
            if (quad == 0) rsp[(size_t)gid * 48 + mi * 16 + lane] = rs[mi];
        }
    }
}

// ---------------- reduce chunks, normalize, assemble R ----------------
__global__ __launch_bounds__(256) void k_rows2(const float* __restrict__ Op,
                                               const float* __restrict__ rsp,
                                               float* __restrict__ R, int U) {
    __shared__ float inv[48];
    __shared__ float msum[4][64];
    int bh = blockIdx.x;
    int b = bh >> 4, h = bh & (H_ - 1);
    int tid = threadIdx.x;
    if (tid < 48) {
        float s = 0.f;
        for (int cc = 0; cc < NC_; ++cc) s += rsp[(size_t)(bh * NC_ + cc) * 48 + tid];
        inv[tid] = 1.f / s;
    }
    __syncthreads();
    int dh = tid & 63, ig = tid >> 6;
    float acc = 0.f;
    for (int p = 0; p < 11; ++p) {
        int i = p * 4 + ig;
        if (i < U) {
            float o = 0.f;
            for (int cc = 0; cc < NC_; ++cc)
                o += Op[((size_t)(bh * NC_ + cc) * 48 + i) * DH_ + dh];
            float v = o * inv[i];
            R[((size_t)b * (U + 1) + 1 + i) * D_ + h * DH_ + dh] = v;
            acc += v;
        }
    }
    msum[ig][dh] = acc;
    __syncthreads();
    if (ig == 0)
        R[((size_t)b * (U + 1)) * D_ + h * DH_ + dh] =
            (msum[0][dh] + msum[1][dh] + msum[2][dh] + msum[3][dh]) / (float)U;
}

__global__ __launch_bounds__(256) void k_fill(const float* __restrict__ Yr,
                                              const int* __restrict__ sel,
                                              float* __restrict__ y, int U) {
    int blk = blockIdx.x;
    int b = blk >> 12, t = blk & (T_ - 1);
    int j = sel[t];
    const float4* src = (const float4*)(Yr + ((size_t)b * (U + 1) + j) * D_);
    float4* dst = (float4*)(y + (size_t)blk * D_);
    dst[threadIdx.x] = src[threadIdx.x];
}

extern "C" void kernel_launch(void* const* d_in, const int* in_sizes, int n_in,
                              void* d_out, int out_size, void* d_ws, size_t ws_size,
                              hipStream_t stream) {
    const float* x  = (const float*)d_in[0];
    const float* Wq = (const float*)d_in[1];
    const float* Wk = (const float*)d_in[2];
    const float* Wv = (const float*)d_in[3];
    const float* Wo = (const float*)d_in[4];
    const float* bo = (const float*)d_in[5];
    const int*  idx = (const int*)d_in[6];
    int U = in_sizes[6];                      // 41
    int HU = H_ * U;                          // 656
    int MP = ((HU + 127) / 128) * 128;        // 768

    char* w = (char*)d_ws;
    auto alloc = [&](size_t bytes) { char* p = w; w += (bytes + 255) & ~(size_t)255; return p; };

    float* xs    = (float*)alloc((size_t)B_ * U * D_ * 4);
    float* Qs    = (float*)alloc((size_t)B_ * U * D_ * 4);
    short* Qtb   = (short*)alloc((size_t)B_ * MP * D_ * 2);
    short* xb    = (short*)alloc((size_t)B_ * T_ * D_ * 2);
    short* Wvb   = (short*)alloc((size_t)D_ * D_ * 2);
    short* attnb = (short*)alloc((size_t)B_ * MP * T_ * 2);
    short* Vtb   = (short*)alloc((size_t)B_ * D_ * T_ * 2);
    float* Opb   = (float*)alloc((size_t)B_ * H_ * NC_ * 48 * DH_ * 4);
    float* rspb  = (float*)alloc((size_t)B_ * H_ * NC_ * 48 * 4);
    float* R     = (float*)alloc((size_t)B_ * (U + 1) * D_ * 4);
    float* Yr    = (float*)alloc((size_t)B_ * (U + 1) * D_ * 4);
    int*   sel   = (int*)alloc((size_t)T_ * 4);

    k_sel<<<dim3(1), dim3(256), 0, stream>>>(idx, sel, U);
    k_gather<<<dim3(B_ * U), dim3(256), 0, stream>>>(x, idx, xs, U);
    k_proj<<<dim3((B_ * U + 63) / 64, D_ / 64), dim3(256), 0, stream>>>(xs, Wq, nullptr, Qs, B_ * U);
    k_cvt_flat<<<dim3((size_t)B_ * T_ * D_ / 2048), dim3(256), 0, stream>>>(x, xb);
    k_cvt_flat<<<dim3((size_t)D_ * D_ / 2048), dim3(256), 0, stream>>>(Wv, Wvb);
    k_qth<<<dim3((B_ * U + 63) / 64, D_ / 64, H_), dim3(256), 0, stream>>>(Qs, Wk, Qtb, U, MP);
    k_gemm<<<dim3(512 + B_ * 48), dim3(512), 0, stream>>>(Qtb, xb, Wvb, attnb, Vtb, MP);
    k_pv<<<dim3(B_ * H_ * NC_), dim3(256), 0, stream>>>(attnb, Vtb, Opb, rspb, U, MP);
    k_rows2<<<dim3(B_ * H_), dim3(256), 0, stream>>>(Opb, rspb, R, U);
    k_proj<<<dim3((B_ * (U + 1) + 63) / 64, D_ / 64), dim3(256), 0, stream>>>(R, Wo, bo, Yr, B_ * (U + 1));
    k_fill<<<dim3(B_ * T_), dim3(256), 0, stream>>>(Yr, sel, (float*)d_out, U);
}